// Round 1
// baseline (289.236 us; speedup 1.0000x reference)
//
#include <hip/hip_runtime.h>
#include <math.h>

static constexpr int DIM   = 33;
static constexpr int LUT_N = DIM * DIM * DIM;      // 35937
static constexpr int HW    = 1024 * 1024;
static constexpr int BATCH = 8;
static constexpr long NPIX = (long)BATCH * HW;     // 8388608

// ---------------------------------------------------------------------------
// Repack LUT from SoA (3, 33^3) to AoS float4 (33^3) so each trilinear corner
// is one 16B load and r-adjacent corners share a cacheline.
// ---------------------------------------------------------------------------
__global__ __launch_bounds__(256) void repack_lut_kernel(
    const float* __restrict__ lut, float4* __restrict__ packed) {
    int i = blockIdx.x * 256 + threadIdx.x;
    if (i < LUT_N) {
        packed[i] = make_float4(lut[i], lut[LUT_N + i], lut[2 * LUT_N + i], 0.0f);
    }
}

__device__ __forceinline__ float4 f4_lerp(float4 a, float4 b, float t) {
    return make_float4(fmaf(t, b.x - a.x, a.x),
                       fmaf(t, b.y - a.y, a.y),
                       fmaf(t, b.z - a.z, a.z),
                       0.0f);
}

__device__ __forceinline__ void trilerp(const float4* __restrict__ lutp,
                                        float r, float g, float b,
                                        float& outr, float& outg, float& outb) {
    const float scale = (float)(DIM - 1);
    float rs = r * scale, gs = g * scale, bs = b * scale;
    int ir = (int)floorf(rs); ir = ir < 0 ? 0 : (ir > DIM - 2 ? DIM - 2 : ir);
    int ig = (int)floorf(gs); ig = ig < 0 ? 0 : (ig > DIM - 2 ? DIM - 2 : ig);
    int ib = (int)floorf(bs); ib = ib < 0 ? 0 : (ib > DIM - 2 ? DIM - 2 : ib);
    float fr = rs - (float)ir;
    float fg = gs - (float)ig;
    float fb = bs - (float)ib;
    int base = (ib * DIM + ig) * DIM + ir;

    float4 c000 = lutp[base];
    float4 c001 = lutp[base + 1];
    float4 c010 = lutp[base + DIM];
    float4 c011 = lutp[base + DIM + 1];
    float4 c100 = lutp[base + DIM * DIM];
    float4 c101 = lutp[base + DIM * DIM + 1];
    float4 c110 = lutp[base + DIM * DIM + DIM];
    float4 c111 = lutp[base + DIM * DIM + DIM + 1];

    float4 a00 = f4_lerp(c000, c001, fr);
    float4 a01 = f4_lerp(c010, c011, fr);
    float4 a10 = f4_lerp(c100, c101, fr);
    float4 a11 = f4_lerp(c110, c111, fr);
    float4 b0  = f4_lerp(a00, a01, fg);
    float4 b1  = f4_lerp(a10, a11, fg);
    float4 cc  = f4_lerp(b0, b1, fb);
    outr = cc.x; outg = cc.y; outb = cc.z;
}

// ---------------------------------------------------------------------------
// Main kernel: each thread handles 4 consecutive pixels (same b, same row) so
// all global traffic is float4-coalesced. x / out layout: (B, 3, H, W).
// ---------------------------------------------------------------------------
__global__ __launch_bounds__(256) void lut_apply_vec4(
    const float* __restrict__ x, const float4* __restrict__ lutp,
    float* __restrict__ out) {
    long t = (long)blockIdx.x * 256 + threadIdx.x;  // [0, NPIX/4)
    long p = t * 4;                                  // pixel linear index
    int  b  = (int)(p >> 20);                        // p / HW
    int  hw = (int)(p & (HW - 1));
    size_t base = (size_t)b * (3 * (size_t)HW) + (size_t)hw;

    float4 rv = *(const float4*)(x + base);
    float4 gv = *(const float4*)(x + base + (size_t)HW);
    float4 bv = *(const float4*)(x + base + 2 * (size_t)HW);

    float rr[4] = {rv.x, rv.y, rv.z, rv.w};
    float gg[4] = {gv.x, gv.y, gv.z, gv.w};
    float bb[4] = {bv.x, bv.y, bv.z, bv.w};
    float orr[4], org[4], orb[4];

#pragma unroll
    for (int i = 0; i < 4; ++i) {
        trilerp(lutp, rr[i], gg[i], bb[i], orr[i], org[i], orb[i]);
    }

    *(float4*)(out + base)                  = make_float4(orr[0], orr[1], orr[2], orr[3]);
    *(float4*)(out + base + (size_t)HW)     = make_float4(org[0], org[1], org[2], org[3]);
    *(float4*)(out + base + 2 * (size_t)HW) = make_float4(orb[0], orb[1], orb[2], orb[3]);
}

// ---------------------------------------------------------------------------
// Fallback: read LUT directly in SoA layout (24 scalar gathers/pixel) in case
// ws_size is too small for the repacked table. Correctness safety net only.
// ---------------------------------------------------------------------------
__global__ __launch_bounds__(256) void lut_apply_soa(
    const float* __restrict__ x, const float* __restrict__ lut,
    float* __restrict__ out) {
    long t = (long)blockIdx.x * 256 + threadIdx.x;
    long p = t * 4;
    int  b  = (int)(p >> 20);
    int  hw = (int)(p & (HW - 1));
    size_t base = (size_t)b * (3 * (size_t)HW) + (size_t)hw;

    float4 rv = *(const float4*)(x + base);
    float4 gv = *(const float4*)(x + base + (size_t)HW);
    float4 bv = *(const float4*)(x + base + 2 * (size_t)HW);

    float rr[4] = {rv.x, rv.y, rv.z, rv.w};
    float gg[4] = {gv.x, gv.y, gv.z, gv.w};
    float bb[4] = {bv.x, bv.y, bv.z, bv.w};
    float orr[4], org[4], orb[4];

#pragma unroll
    for (int i = 0; i < 4; ++i) {
        const float scale = (float)(DIM - 1);
        float rs = rr[i] * scale, gs = gg[i] * scale, bs = bb[i] * scale;
        int ir = (int)floorf(rs); ir = ir < 0 ? 0 : (ir > DIM - 2 ? DIM - 2 : ir);
        int ig = (int)floorf(gs); ig = ig < 0 ? 0 : (ig > DIM - 2 ? DIM - 2 : ig);
        int ib = (int)floorf(bs); ib = ib < 0 ? 0 : (ib > DIM - 2 ? DIM - 2 : ib);
        float fr = rs - (float)ir, fg = gs - (float)ig, fb = bs - (float)ib;
        int base_i = (ib * DIM + ig) * DIM + ir;
        float acc[3] = {0.f, 0.f, 0.f};
#pragma unroll
        for (int db = 0; db < 2; ++db) {
            float wb = db ? fb : 1.f - fb;
#pragma unroll
            for (int dg = 0; dg < 2; ++dg) {
                float wg = dg ? fg : 1.f - fg;
#pragma unroll
                for (int dr = 0; dr < 2; ++dr) {
                    float wr = dr ? fr : 1.f - fr;
                    int idx = base_i + (db * DIM + dg) * DIM + dr;
                    float w = wb * wg * wr;
                    acc[0] = fmaf(w, lut[idx], acc[0]);
                    acc[1] = fmaf(w, lut[LUT_N + idx], acc[1]);
                    acc[2] = fmaf(w, lut[2 * LUT_N + idx], acc[2]);
                }
            }
        }
        orr[i] = acc[0]; org[i] = acc[1]; orb[i] = acc[2];
    }

    *(float4*)(out + base)                  = make_float4(orr[0], orr[1], orr[2], orr[3]);
    *(float4*)(out + base + (size_t)HW)     = make_float4(org[0], org[1], org[2], org[3]);
    *(float4*)(out + base + 2 * (size_t)HW) = make_float4(orb[0], orb[1], orb[2], orb[3]);
}

extern "C" void kernel_launch(void* const* d_in, const int* in_sizes, int n_in,
                              void* d_out, int out_size, void* d_ws, size_t ws_size,
                              hipStream_t stream) {
    // setup_inputs order: {'lut', 'x'}; guard on sizes anyway.
    const float* lut = (const float*)d_in[0];
    const float* x   = (const float*)d_in[1];
    if (n_in >= 2 && in_sizes[0] > in_sizes[1]) {  // swapped
        lut = (const float*)d_in[1];
        x   = (const float*)d_in[0];
    }
    float* out = (float*)d_out;

    const long nthreads = NPIX / 4;        // 2,097,152
    const int  block    = 256;
    const int  grid     = (int)(nthreads / block);  // 8192

    const size_t need = (size_t)LUT_N * sizeof(float4);
    if (ws_size >= need) {
        float4* packed = (float4*)d_ws;
        repack_lut_kernel<<<(LUT_N + 255) / 256, 256, 0, stream>>>(lut, packed);
        lut_apply_vec4<<<grid, block, 0, stream>>>(x, packed, out);
    } else {
        lut_apply_soa<<<grid, block, 0, stream>>>(x, lut, out);
    }
}

// Round 2
// 282.848 us; speedup vs baseline: 1.0226x; 1.0226x over previous
//
#include <hip/hip_runtime.h>
#include <hip/hip_fp16.h>
#include <math.h>

static constexpr int DIM    = 33;
static constexpr int LUT_N  = DIM * DIM * DIM;          // 35937
static constexpr int RCELLS = DIM - 1;                  // 32 r-cells per (g,b)
static constexpr int PK_N   = DIM * DIM * RCELLS;       // 34848 packed entries
static constexpr int HW     = 1024 * 1024;
static constexpr int BATCH  = 8;
static constexpr long NPIX  = (long)BATCH * HW;         // 8388608

// ---------------------------------------------------------------------------
// Repack LUT: SoA fp32 (3, 33^3) -> fp16 corner-pair table indexed
// [b][g][r_cell], each 16B entry = {r0,g0,b0, r1,g1,b1, pad, pad} fp16.
// One dwordx4 gather then yields BOTH r-adjacent corners (4 gathers/pixel).
// ---------------------------------------------------------------------------
__global__ __launch_bounds__(256) void repack_lut_fp16pair(
    const float* __restrict__ lut, uint4* __restrict__ pk) {
    int i = blockIdx.x * 256 + threadIdx.x;
    if (i >= PK_N) return;
    int rc = i & 31;            // r_cell  (RCELLS = 32 -> power of two)
    int g  = (i >> 5) % DIM;
    int b  = (i >> 5) / DIM;
    int s  = (b * DIM + g) * DIM + rc;   // SoA index of corner r0
    __half h0r = __float2half(lut[s]);
    __half h0g = __float2half(lut[LUT_N + s]);
    __half h0b = __float2half(lut[2 * LUT_N + s]);
    __half h1r = __float2half(lut[s + 1]);
    __half h1g = __float2half(lut[LUT_N + s + 1]);
    __half h1b = __float2half(lut[2 * LUT_N + s + 1]);
    uint4 v;
    v.x = (unsigned)__half_as_ushort(h0r) | ((unsigned)__half_as_ushort(h0g) << 16);
    v.y = (unsigned)__half_as_ushort(h0b) | ((unsigned)__half_as_ushort(h1r) << 16);
    v.z = (unsigned)__half_as_ushort(h1g) | ((unsigned)__half_as_ushort(h1b) << 16);
    v.w = 0;
    pk[i] = v;
}

// Unpack one 16B entry into two fp32 RGB corners, r-lerp them with fr.
__device__ __forceinline__ void pair_rlerp(uint4 v, float fr, float o[3]) {
    __half2 ha = *(__half2*)&v.x;   // r0, g0
    __half2 hb = *(__half2*)&v.y;   // b0, r1
    __half2 hc = *(__half2*)&v.z;   // g1, b1
    float2 fa = __half22float2(ha);
    float2 fb = __half22float2(hb);
    float2 fc = __half22float2(hc);
    o[0] = fmaf(fr, fa.x * -1.0f + fc.y * 0.0f + (fb.y - fa.x), fa.x); // placeholder avoided below
    // (written explicitly for clarity:)
    o[0] = fmaf(fr, fb.y - fa.x, fa.x);
    o[1] = fmaf(fr, fc.x - fa.y, fa.y);
    o[2] = fmaf(fr, fc.y - fb.x, fb.x);
}

__device__ __forceinline__ void trilerp_pk(const uint4* __restrict__ pk,
                                           float r, float g, float b,
                                           float& outr, float& outg, float& outb) {
    const float scale = (float)(DIM - 1);
    float rs = r * scale, gs = g * scale, bs = b * scale;
    int ir = (int)floorf(rs); ir = ir < 0 ? 0 : (ir > DIM - 2 ? DIM - 2 : ir);
    int ig = (int)floorf(gs); ig = ig < 0 ? 0 : (ig > DIM - 2 ? DIM - 2 : ig);
    int ib = (int)floorf(bs); ib = ib < 0 ? 0 : (ib > DIM - 2 ? DIM - 2 : ib);
    float fr = rs - (float)ir;
    float fg = gs - (float)ig;
    float fb = bs - (float)ib;

    int base = (ib * DIM + ig) * RCELLS + ir;     // [b][g][r_cell]
    uint4 v00 = pk[base];                          // (ib  , ig  )
    uint4 v01 = pk[base + RCELLS];                 // (ib  , ig+1)
    uint4 v10 = pk[base + DIM * RCELLS];           // (ib+1, ig  )
    uint4 v11 = pk[base + DIM * RCELLS + RCELLS];  // (ib+1, ig+1)

    float c00[3], c01[3], c10[3], c11[3];
    pair_rlerp(v00, fr, c00);
    pair_rlerp(v01, fr, c01);
    pair_rlerp(v10, fr, c10);
    pair_rlerp(v11, fr, c11);

    float g0[3], g1[3];
#pragma unroll
    for (int ch = 0; ch < 3; ++ch) {
        g0[ch] = fmaf(fg, c01[ch] - c00[ch], c00[ch]);
        g1[ch] = fmaf(fg, c11[ch] - c10[ch], c10[ch]);
    }
    outr = fmaf(fb, g1[0] - g0[0], g0[0]);
    outg = fmaf(fb, g1[1] - g0[1], g0[1]);
    outb = fmaf(fb, g1[2] - g0[2], g0[2]);
}

// ---------------------------------------------------------------------------
// Main kernel: each thread handles 4 consecutive pixels -> float4 coalesced
// global IO; 16 outstanding gathers/thread for latency hiding.
// ---------------------------------------------------------------------------
__global__ __launch_bounds__(256) void lut_apply_pk(
    const float* __restrict__ x, const uint4* __restrict__ pk,
    float* __restrict__ out) {
    long t = (long)blockIdx.x * 256 + threadIdx.x;  // [0, NPIX/4)
    long p = t * 4;
    int  b  = (int)(p >> 20);
    int  hw = (int)(p & (HW - 1));
    size_t base = (size_t)b * (3 * (size_t)HW) + (size_t)hw;

    float4 rv = *(const float4*)(x + base);
    float4 gv = *(const float4*)(x + base + (size_t)HW);
    float4 bv = *(const float4*)(x + base + 2 * (size_t)HW);

    float rr[4] = {rv.x, rv.y, rv.z, rv.w};
    float gg[4] = {gv.x, gv.y, gv.z, gv.w};
    float bb[4] = {bv.x, bv.y, bv.z, bv.w};
    float orr[4], org[4], orb[4];

#pragma unroll
    for (int i = 0; i < 4; ++i) {
        trilerp_pk(pk, rr[i], gg[i], bb[i], orr[i], org[i], orb[i]);
    }

    *(float4*)(out + base)                  = make_float4(orr[0], orr[1], orr[2], orr[3]);
    *(float4*)(out + base + (size_t)HW)     = make_float4(org[0], org[1], org[2], org[3]);
    *(float4*)(out + base + 2 * (size_t)HW) = make_float4(orb[0], orb[1], orb[2], orb[3]);
}

// ---------------------------------------------------------------------------
// Fallback: direct SoA gathers (no workspace needed). Safety net only.
// ---------------------------------------------------------------------------
__global__ __launch_bounds__(256) void lut_apply_soa(
    const float* __restrict__ x, const float* __restrict__ lut,
    float* __restrict__ out) {
    long t = (long)blockIdx.x * 256 + threadIdx.x;
    long p = t * 4;
    int  b  = (int)(p >> 20);
    int  hw = (int)(p & (HW - 1));
    size_t base = (size_t)b * (3 * (size_t)HW) + (size_t)hw;

    float4 rv = *(const float4*)(x + base);
    float4 gv = *(const float4*)(x + base + (size_t)HW);
    float4 bv = *(const float4*)(x + base + 2 * (size_t)HW);

    float rr[4] = {rv.x, rv.y, rv.z, rv.w};
    float gg[4] = {gv.x, gv.y, gv.z, gv.w};
    float bb[4] = {bv.x, bv.y, bv.z, bv.w};
    float orr[4], org[4], orb[4];

#pragma unroll
    for (int i = 0; i < 4; ++i) {
        const float scale = (float)(DIM - 1);
        float rs = rr[i] * scale, gs = gg[i] * scale, bs = bb[i] * scale;
        int ir = (int)floorf(rs); ir = ir < 0 ? 0 : (ir > DIM - 2 ? DIM - 2 : ir);
        int ig = (int)floorf(gs); ig = ig < 0 ? 0 : (ig > DIM - 2 ? DIM - 2 : ig);
        int ib = (int)floorf(bs); ib = ib < 0 ? 0 : (ib > DIM - 2 ? DIM - 2 : ib);
        float fr = rs - (float)ir, fg = gs - (float)ig, fb = bs - (float)ib;
        int base_i = (ib * DIM + ig) * DIM + ir;
        float acc[3] = {0.f, 0.f, 0.f};
#pragma unroll
        for (int db = 0; db < 2; ++db) {
            float wb = db ? fb : 1.f - fb;
#pragma unroll
            for (int dg = 0; dg < 2; ++dg) {
                float wg = dg ? fg : 1.f - fg;
#pragma unroll
                for (int dr = 0; dr < 2; ++dr) {
                    float wr = dr ? fr : 1.f - fr;
                    int idx = base_i + (db * DIM + dg) * DIM + dr;
                    float w = wb * wg * wr;
                    acc[0] = fmaf(w, lut[idx], acc[0]);
                    acc[1] = fmaf(w, lut[LUT_N + idx], acc[1]);
                    acc[2] = fmaf(w, lut[2 * LUT_N + idx], acc[2]);
                }
            }
        }
        orr[i] = acc[0]; org[i] = acc[1]; orb[i] = acc[2];
    }

    *(float4*)(out + base)                  = make_float4(orr[0], orr[1], orr[2], orr[3]);
    *(float4*)(out + base + (size_t)HW)     = make_float4(org[0], org[1], org[2], org[3]);
    *(float4*)(out + base + 2 * (size_t)HW) = make_float4(orb[0], orb[1], orb[2], orb[3]);
}

extern "C" void kernel_launch(void* const* d_in, const int* in_sizes, int n_in,
                              void* d_out, int out_size, void* d_ws, size_t ws_size,
                              hipStream_t stream) {
    const float* lut = (const float*)d_in[0];
    const float* x   = (const float*)d_in[1];
    if (n_in >= 2 && in_sizes[0] > in_sizes[1]) {  // defensive: order swapped
        lut = (const float*)d_in[1];
        x   = (const float*)d_in[0];
    }
    float* out = (float*)d_out;

    const long nthreads = NPIX / 4;                 // 2,097,152
    const int  block    = 256;
    const int  grid     = (int)(nthreads / block);  // 8192

    const size_t need = (size_t)PK_N * sizeof(uint4);  // 557,568 B
    if (ws_size >= need) {
        uint4* pk = (uint4*)d_ws;
        repack_lut_fp16pair<<<(PK_N + 255) / 256, 256, 0, stream>>>(lut, pk);
        lut_apply_pk<<<grid, block, 0, stream>>>(x, pk, out);
    } else {
        lut_apply_soa<<<grid, block, 0, stream>>>(x, lut, out);
    }
}

// Round 3
// 273.292 us; speedup vs baseline: 1.0583x; 1.0350x over previous
//
#include <hip/hip_runtime.h>
#include <math.h>

static constexpr int DIM    = 33;
static constexpr int LUT_N  = DIM * DIM * DIM;          // 35937
static constexpr int CELLS  = 32;                       // cells per axis
static constexpr int NCELL  = CELLS * CELLS * CELLS;    // 32768
static constexpr int HW     = 1024 * 1024;
static constexpr int BATCH  = 8;
static constexpr long NPIX  = (long)BATCH * HW;         // 8388608

// ws layout: [0, 1MB) quad-cell table (uint4 pairs), then 2 floats {min,max}.
static constexpr size_t QT_BYTES = (size_t)NCELL * 32;  // 1,048,576
static constexpr size_t MM_OFF   = QT_BYTES;

// ---------------------------------------------------------------------------
// Pass 1: min/max of the LUT (single block) for range-normalized quantization.
// ---------------------------------------------------------------------------
__global__ __launch_bounds__(1024) void lut_minmax(
    const float* __restrict__ lut, float* __restrict__ mm) {
    __shared__ float smin[1024], smax[1024];
    int t = threadIdx.x;
    float vmin = 1e30f, vmax = -1e30f;
    for (int i = t; i < 3 * LUT_N; i += 1024) {
        float v = lut[i];
        vmin = fminf(vmin, v);
        vmax = fmaxf(vmax, v);
    }
    smin[t] = vmin; smax[t] = vmax;
    __syncthreads();
    for (int s = 512; s > 0; s >>= 1) {
        if (t < s) {
            smin[t] = fminf(smin[t], smin[t + s]);
            smax[t] = fmaxf(smax[t], smax[t + s]);
        }
        __syncthreads();
    }
    if (t == 0) { mm[0] = smin[0]; mm[1] = smax[0]; }
}

// ---------------------------------------------------------------------------
// Pass 2: build quad-cell table. Cell (cb,cg,cr) -> 8 corners, each corner
// packed u10 r|g<<10|b<<20 in one u32; 8 u32 = 32B per cell, 32B-aligned.
// Corner order: bit0=dr, bit1=dg, bit2=db  (lo uint4 = db0, hi uint4 = db1).
// ---------------------------------------------------------------------------
__global__ __launch_bounds__(256) void repack_qcell(
    const float* __restrict__ lut, uint4* __restrict__ qt,
    const float* __restrict__ mm) {
    int i = blockIdx.x * 256 + threadIdx.x;   // cell id < 32768
    float mn = mm[0], mx = mm[1];
    float range = mx - mn;
    if (range < 1e-20f) range = 1e-20f;
    float scale = 1023.0f / range;
    int cr = i & 31, cg = (i >> 5) & 31, cb = i >> 10;
    unsigned w[8];
#pragma unroll
    for (int c = 0; c < 8; ++c) {
        int dr = c & 1, dg = (c >> 1) & 1, db = c >> 2;
        int s = ((cb + db) * DIM + (cg + dg)) * DIM + (cr + dr);
        unsigned qr = (unsigned)__float2int_rn((lut[s] - mn) * scale);
        unsigned qg = (unsigned)__float2int_rn((lut[LUT_N + s] - mn) * scale);
        unsigned qb = (unsigned)__float2int_rn((lut[2 * LUT_N + s] - mn) * scale);
        w[c] = qr | (qg << 10) | (qb << 20);
    }
    qt[2 * i]     = make_uint4(w[0], w[1], w[2], w[3]);
    qt[2 * i + 1] = make_uint4(w[4], w[5], w[6], w[7]);
}

__device__ __forceinline__ void dec10(unsigned w, float o[3]) {
    o[0] = (float)(w & 1023u);
    o[1] = (float)((w >> 10) & 1023u);
    o[2] = (float)(w >> 20);
}

// ---------------------------------------------------------------------------
// Pass 3: apply. 4 consecutive pixels per thread (float4 IO). Per pixel:
// exactly ONE 32B quad-cell entry -> 2 dwordx4 loads, 1 distinct cacheline.
// ---------------------------------------------------------------------------
__global__ __launch_bounds__(256) void lut_apply_q(
    const float* __restrict__ x, const uint4* __restrict__ qt,
    const float* __restrict__ mm, float* __restrict__ out) {
    long t = (long)blockIdx.x * 256 + threadIdx.x;  // [0, NPIX/4)
    long p = t * 4;
    int  b  = (int)(p >> 20);
    int  hw = (int)(p & (HW - 1));
    size_t base = (size_t)b * (3 * (size_t)HW) + (size_t)hw;

    float mn = mm[0];
    float range = mm[1] - mn;
    if (range < 1e-20f) range = 1e-20f;
    float inv = range * (1.0f / 1023.0f);

    float4 rv = *(const float4*)(x + base);
    float4 gv = *(const float4*)(x + base + (size_t)HW);
    float4 bv = *(const float4*)(x + base + 2 * (size_t)HW);

    float rr[4] = {rv.x, rv.y, rv.z, rv.w};
    float gg[4] = {gv.x, gv.y, gv.z, gv.w};
    float bb[4] = {bv.x, bv.y, bv.z, bv.w};
    float orr[4], org[4], orb[4];

#pragma unroll
    for (int i = 0; i < 4; ++i) {
        const float scale = (float)(DIM - 1);
        float rs = rr[i] * scale, gs = gg[i] * scale, bs = bb[i] * scale;
        int ir = (int)floorf(rs); ir = ir < 0 ? 0 : (ir > DIM - 2 ? DIM - 2 : ir);
        int ig = (int)floorf(gs); ig = ig < 0 ? 0 : (ig > DIM - 2 ? DIM - 2 : ig);
        int ib = (int)floorf(bs); ib = ib < 0 ? 0 : (ib > DIM - 2 ? DIM - 2 : ib);
        float fr = rs - (float)ir;
        float fg = gs - (float)ig;
        float fb = bs - (float)ib;

        int cell = (ib * CELLS + ig) * CELLS + ir;
        uint4 lo = qt[2 * cell];
        uint4 hi = qt[2 * cell + 1];

        float c000[3], c001[3], c010[3], c011[3];
        float c100[3], c101[3], c110[3], c111[3];
        dec10(lo.x, c000); dec10(lo.y, c001); dec10(lo.z, c010); dec10(lo.w, c011);
        dec10(hi.x, c100); dec10(hi.y, c101); dec10(hi.z, c110); dec10(hi.w, c111);

        float q[3];
#pragma unroll
        for (int ch = 0; ch < 3; ++ch) {
            float a00 = fmaf(fr, c001[ch] - c000[ch], c000[ch]);
            float a01 = fmaf(fr, c011[ch] - c010[ch], c010[ch]);
            float a10 = fmaf(fr, c101[ch] - c100[ch], c100[ch]);
            float a11 = fmaf(fr, c111[ch] - c110[ch], c110[ch]);
            float g0  = fmaf(fg, a01 - a00, a00);
            float g1  = fmaf(fg, a11 - a10, a10);
            q[ch]     = fmaf(fb, g1 - g0, g0);
        }
        orr[i] = fmaf(q[0], inv, mn);
        org[i] = fmaf(q[1], inv, mn);
        orb[i] = fmaf(q[2], inv, mn);
    }

    *(float4*)(out + base)                  = make_float4(orr[0], orr[1], orr[2], orr[3]);
    *(float4*)(out + base + (size_t)HW)     = make_float4(org[0], org[1], org[2], org[3]);
    *(float4*)(out + base + 2 * (size_t)HW) = make_float4(orb[0], orb[1], orb[2], orb[3]);
}

// ---------------------------------------------------------------------------
// Fallback: direct SoA gathers (no workspace needed). Safety net only.
// ---------------------------------------------------------------------------
__global__ __launch_bounds__(256) void lut_apply_soa(
    const float* __restrict__ x, const float* __restrict__ lut,
    float* __restrict__ out) {
    long t = (long)blockIdx.x * 256 + threadIdx.x;
    long p = t * 4;
    int  b  = (int)(p >> 20);
    int  hw = (int)(p & (HW - 1));
    size_t base = (size_t)b * (3 * (size_t)HW) + (size_t)hw;

    float4 rv = *(const float4*)(x + base);
    float4 gv = *(const float4*)(x + base + (size_t)HW);
    float4 bv = *(const float4*)(x + base + 2 * (size_t)HW);

    float rr[4] = {rv.x, rv.y, rv.z, rv.w};
    float gg[4] = {gv.x, gv.y, gv.z, gv.w};
    float bb[4] = {bv.x, bv.y, bv.z, bv.w};
    float orr[4], org[4], orb[4];

#pragma unroll
    for (int i = 0; i < 4; ++i) {
        const float scale = (float)(DIM - 1);
        float rs = rr[i] * scale, gs = gg[i] * scale, bs = bb[i] * scale;
        int ir = (int)floorf(rs); ir = ir < 0 ? 0 : (ir > DIM - 2 ? DIM - 2 : ir);
        int ig = (int)floorf(gs); ig = ig < 0 ? 0 : (ig > DIM - 2 ? DIM - 2 : ig);
        int ib = (int)floorf(bs); ib = ib < 0 ? 0 : (ib > DIM - 2 ? DIM - 2 : ib);
        float fr = rs - (float)ir, fg = gs - (float)ig, fb = bs - (float)ib;
        int base_i = (ib * DIM + ig) * DIM + ir;
        float acc[3] = {0.f, 0.f, 0.f};
#pragma unroll
        for (int db = 0; db < 2; ++db) {
            float wb = db ? fb : 1.f - fb;
#pragma unroll
            for (int dg = 0; dg < 2; ++dg) {
                float wg = dg ? fg : 1.f - fg;
#pragma unroll
                for (int dr = 0; dr < 2; ++dr) {
                    float wr = dr ? fr : 1.f - fr;
                    int idx = base_i + (db * DIM + dg) * DIM + dr;
                    float w = wb * wg * wr;
                    acc[0] = fmaf(w, lut[idx], acc[0]);
                    acc[1] = fmaf(w, lut[LUT_N + idx], acc[1]);
                    acc[2] = fmaf(w, lut[2 * LUT_N + idx], acc[2]);
                }
            }
        }
        orr[i] = acc[0]; org[i] = acc[1]; orb[i] = acc[2];
    }

    *(float4*)(out + base)                  = make_float4(orr[0], orr[1], orr[2], orr[3]);
    *(float4*)(out + base + (size_t)HW)     = make_float4(org[0], org[1], org[2], org[3]);
    *(float4*)(out + base + 2 * (size_t)HW) = make_float4(orb[0], orb[1], orb[2], orb[3]);
}

extern "C" void kernel_launch(void* const* d_in, const int* in_sizes, int n_in,
                              void* d_out, int out_size, void* d_ws, size_t ws_size,
                              hipStream_t stream) {
    const float* lut = (const float*)d_in[0];
    const float* x   = (const float*)d_in[1];
    if (n_in >= 2 && in_sizes[0] > in_sizes[1]) {  // defensive: order swapped
        lut = (const float*)d_in[1];
        x   = (const float*)d_in[0];
    }
    float* out = (float*)d_out;

    const long nthreads = NPIX / 4;                 // 2,097,152
    const int  block    = 256;
    const int  grid     = (int)(nthreads / block);  // 8192

    const size_t need = QT_BYTES + 2 * sizeof(float);
    if (ws_size >= need) {
        uint4* qt = (uint4*)d_ws;
        float* mm = (float*)((char*)d_ws + MM_OFF);
        lut_minmax<<<1, 1024, 0, stream>>>(lut, mm);
        repack_qcell<<<NCELL / 256, 256, 0, stream>>>(lut, qt, mm);
        lut_apply_q<<<grid, block, 0, stream>>>(x, qt, mm, out);
    } else {
        lut_apply_soa<<<grid, block, 0, stream>>>(x, lut, out);
    }
}

// Round 4
// 239.080 us; speedup vs baseline: 1.2098x; 1.1431x over previous
//
#include <hip/hip_runtime.h>
#include <math.h>

static constexpr int DIM    = 33;
static constexpr int LUT_N  = DIM * DIM * DIM;          // 35937
static constexpr int HW     = 1024 * 1024;
static constexpr int BATCH  = 8;
static constexpr long NPIX  = (long)BATCH * HW;         // 8388608
static constexpr long NTASK = NPIX / 4;                 // 2,097,152 (4 px/task)

static constexpr size_t QT_BYTES = (size_t)LUT_N * 4;   // 143,748 B
static constexpr size_t MM_OFF   = 143872;              // 128B-aligned, > QT_BYTES
static constexpr size_t LDS_BYTES = QT_BYTES;           // 140.4 KiB of LDS

// ---------------------------------------------------------------------------
// Pass 1: min/max of the LUT (single block) for range-normalized quantization.
// ---------------------------------------------------------------------------
__global__ __launch_bounds__(1024) void lut_minmax(
    const float* __restrict__ lut, float* __restrict__ mm) {
    __shared__ float smin[1024], smax[1024];
    int t = threadIdx.x;
    float vmin = 1e30f, vmax = -1e30f;
    for (int i = t; i < 3 * LUT_N; i += 1024) {
        float v = lut[i];
        vmin = fminf(vmin, v);
        vmax = fmaxf(vmax, v);
    }
    smin[t] = vmin; smax[t] = vmax;
    __syncthreads();
    for (int s = 512; s > 0; s >>= 1) {
        if (t < s) {
            smin[t] = fminf(smin[t], smin[t + s]);
            smax[t] = fmaxf(smax[t], smax[t + s]);
        }
        __syncthreads();
    }
    if (t == 0) { mm[0] = smin[0]; mm[1] = smax[0]; }
}

// ---------------------------------------------------------------------------
// Pass 2: pack each LUT node as u10 r | g<<10 | b<<20 in one u32 (SoA->node).
// ---------------------------------------------------------------------------
__global__ __launch_bounds__(256) void repack_u10(
    const float* __restrict__ lut, unsigned* __restrict__ qt,
    const float* __restrict__ mm) {
    int i = blockIdx.x * 256 + threadIdx.x;
    if (i >= LUT_N) return;
    float mn = mm[0], mx = mm[1];
    float range = mx - mn;
    if (range < 1e-20f) range = 1e-20f;
    float scale = 1023.0f / range;
    unsigned qr = (unsigned)__float2int_rn((lut[i] - mn) * scale);
    unsigned qg = (unsigned)__float2int_rn((lut[LUT_N + i] - mn) * scale);
    unsigned qb = (unsigned)__float2int_rn((lut[2 * LUT_N + i] - mn) * scale);
    qt[i] = qr | (qg << 10) | (qb << 20);
}

__device__ __forceinline__ void dec10(unsigned w, float o[3]) {
    o[0] = (float)(w & 1023u);
    o[1] = (float)((w >> 10) & 1023u);
    o[2] = (float)(w >> 20);
}

// ---------------------------------------------------------------------------
// Pass 3: apply with the WHOLE u10 LUT resident in LDS (140.4 KiB, gfx950's
// 160 KiB LDS makes this possible). 8 corners = 4x ds_read2_b32 per pixel.
// Persistent-ish: 512 blocks x 1024 threads, grid-stride over 4-px tasks.
// Global IO is pure float4 streaming.
// ---------------------------------------------------------------------------
__global__ __launch_bounds__(1024) void lut_apply_lds(
    const float* __restrict__ x, const unsigned* __restrict__ qt,
    const float* __restrict__ mm, float* __restrict__ out) {
    extern __shared__ unsigned sl[];
    // stage packed LUT into LDS (coalesced dword copy)
    for (int i = threadIdx.x; i < LUT_N; i += 1024) sl[i] = qt[i];
    __syncthreads();

    float mn = mm[0];
    float range = mm[1] - mn;
    if (range < 1e-20f) range = 1e-20f;
    float inv = range * (1.0f / 1023.0f);

    const long T = (long)gridDim.x * 1024;
    for (long t = (long)blockIdx.x * 1024 + threadIdx.x; t < NTASK; t += T) {
        long p = t * 4;
        int  b  = (int)(p >> 20);
        int  hw = (int)(p & (HW - 1));
        size_t base = (size_t)b * (3 * (size_t)HW) + (size_t)hw;

        float4 rv = *(const float4*)(x + base);
        float4 gv = *(const float4*)(x + base + (size_t)HW);
        float4 bv = *(const float4*)(x + base + 2 * (size_t)HW);

        float rr[4] = {rv.x, rv.y, rv.z, rv.w};
        float gg[4] = {gv.x, gv.y, gv.z, gv.w};
        float bb[4] = {bv.x, bv.y, bv.z, bv.w};
        float orr[4], org[4], orb[4];

#pragma unroll
        for (int i = 0; i < 4; ++i) {
            const float scale = (float)(DIM - 1);
            float rs = rr[i] * scale, gs = gg[i] * scale, bs = bb[i] * scale;
            int ir = (int)floorf(rs); ir = ir < 0 ? 0 : (ir > DIM - 2 ? DIM - 2 : ir);
            int ig = (int)floorf(gs); ig = ig < 0 ? 0 : (ig > DIM - 2 ? DIM - 2 : ig);
            int ib = (int)floorf(bs); ib = ib < 0 ? 0 : (ib > DIM - 2 ? DIM - 2 : ib);
            float fr = rs - (float)ir;
            float fg = gs - (float)ig;
            float fb = bs - (float)ib;

            int s = (ib * DIM + ig) * DIM + ir;
            unsigned n000 = sl[s],                 n001 = sl[s + 1];
            unsigned n010 = sl[s + DIM],           n011 = sl[s + DIM + 1];
            unsigned n100 = sl[s + DIM * DIM],     n101 = sl[s + DIM * DIM + 1];
            unsigned n110 = sl[s + DIM * DIM + DIM], n111 = sl[s + DIM * DIM + DIM + 1];

            float c000[3], c001[3], c010[3], c011[3];
            float c100[3], c101[3], c110[3], c111[3];
            dec10(n000, c000); dec10(n001, c001); dec10(n010, c010); dec10(n011, c011);
            dec10(n100, c100); dec10(n101, c101); dec10(n110, c110); dec10(n111, c111);

            float q[3];
#pragma unroll
            for (int ch = 0; ch < 3; ++ch) {
                float a00 = fmaf(fr, c001[ch] - c000[ch], c000[ch]);
                float a01 = fmaf(fr, c011[ch] - c010[ch], c010[ch]);
                float a10 = fmaf(fr, c101[ch] - c100[ch], c100[ch]);
                float a11 = fmaf(fr, c111[ch] - c110[ch], c110[ch]);
                float g0  = fmaf(fg, a01 - a00, a00);
                float g1  = fmaf(fg, a11 - a10, a10);
                q[ch]     = fmaf(fb, g1 - g0, g0);
            }
            orr[i] = fmaf(q[0], inv, mn);
            org[i] = fmaf(q[1], inv, mn);
            orb[i] = fmaf(q[2], inv, mn);
        }

        *(float4*)(out + base)                  = make_float4(orr[0], orr[1], orr[2], orr[3]);
        *(float4*)(out + base + (size_t)HW)     = make_float4(org[0], org[1], org[2], org[3]);
        *(float4*)(out + base + 2 * (size_t)HW) = make_float4(orb[0], orb[1], orb[2], orb[3]);
    }
}

// ---------------------------------------------------------------------------
// Fallback: direct SoA gathers (no workspace needed). Safety net only.
// ---------------------------------------------------------------------------
__global__ __launch_bounds__(256) void lut_apply_soa(
    const float* __restrict__ x, const float* __restrict__ lut,
    float* __restrict__ out) {
    long t = (long)blockIdx.x * 256 + threadIdx.x;
    long p = t * 4;
    int  b  = (int)(p >> 20);
    int  hw = (int)(p & (HW - 1));
    size_t base = (size_t)b * (3 * (size_t)HW) + (size_t)hw;

    float4 rv = *(const float4*)(x + base);
    float4 gv = *(const float4*)(x + base + (size_t)HW);
    float4 bv = *(const float4*)(x + base + 2 * (size_t)HW);

    float rr[4] = {rv.x, rv.y, rv.z, rv.w};
    float gg[4] = {gv.x, gv.y, gv.z, gv.w};
    float bb[4] = {bv.x, bv.y, bv.z, bv.w};
    float orr[4], org[4], orb[4];

#pragma unroll
    for (int i = 0; i < 4; ++i) {
        const float scale = (float)(DIM - 1);
        float rs = rr[i] * scale, gs = gg[i] * scale, bs = bb[i] * scale;
        int ir = (int)floorf(rs); ir = ir < 0 ? 0 : (ir > DIM - 2 ? DIM - 2 : ir);
        int ig = (int)floorf(gs); ig = ig < 0 ? 0 : (ig > DIM - 2 ? DIM - 2 : ig);
        int ib = (int)floorf(bs); ib = ib < 0 ? 0 : (ib > DIM - 2 ? DIM - 2 : ib);
        float fr = rs - (float)ir, fg = gs - (float)ig, fb = bs - (float)ib;
        int base_i = (ib * DIM + ig) * DIM + ir;
        float acc[3] = {0.f, 0.f, 0.f};
#pragma unroll
        for (int db = 0; db < 2; ++db) {
            float wb = db ? fb : 1.f - fb;
#pragma unroll
            for (int dg = 0; dg < 2; ++dg) {
                float wg = dg ? fg : 1.f - fg;
#pragma unroll
                for (int dr = 0; dr < 2; ++dr) {
                    float wr = dr ? fr : 1.f - fr;
                    int idx = base_i + (db * DIM + dg) * DIM + dr;
                    float w = wb * wg * wr;
                    acc[0] = fmaf(w, lut[idx], acc[0]);
                    acc[1] = fmaf(w, lut[LUT_N + idx], acc[1]);
                    acc[2] = fmaf(w, lut[2 * LUT_N + idx], acc[2]);
                }
            }
        }
        orr[i] = acc[0]; org[i] = acc[1]; orb[i] = acc[2];
    }

    *(float4*)(out + base)                  = make_float4(orr[0], orr[1], orr[2], orr[3]);
    *(float4*)(out + base + (size_t)HW)     = make_float4(org[0], org[1], org[2], org[3]);
    *(float4*)(out + base + 2 * (size_t)HW) = make_float4(orb[0], orb[1], orb[2], orb[3]);
}

extern "C" void kernel_launch(void* const* d_in, const int* in_sizes, int n_in,
                              void* d_out, int out_size, void* d_ws, size_t ws_size,
                              hipStream_t stream) {
    const float* lut = (const float*)d_in[0];
    const float* x   = (const float*)d_in[1];
    if (n_in >= 2 && in_sizes[0] > in_sizes[1]) {  // defensive: order swapped
        lut = (const float*)d_in[1];
        x   = (const float*)d_in[0];
    }
    float* out = (float*)d_out;

    const size_t need = MM_OFF + 2 * sizeof(float);
    if (ws_size >= need) {
        unsigned* qt = (unsigned*)d_ws;
        float*    mm = (float*)((char*)d_ws + MM_OFF);
        // Allow >64KB dynamic LDS (gfx950 has 160 KiB). Host-side attr set,
        // idempotent, not a stream op -> graph-capture safe. Ignore status.
        (void)hipFuncSetAttribute((const void*)lut_apply_lds,
                                  hipFuncAttributeMaxDynamicSharedMemorySize,
                                  (int)LDS_BYTES);
        lut_minmax<<<1, 1024, 0, stream>>>(lut, mm);
        repack_u10<<<(LUT_N + 255) / 256, 256, 0, stream>>>(lut, qt, mm);
        lut_apply_lds<<<512, 1024, LDS_BYTES, stream>>>(x, qt, mm, out);
    } else {
        const long nthreads = NTASK;
        lut_apply_soa<<<(int)(nthreads / 256), 256, 0, stream>>>(x, lut, out);
    }
}